// Round 9
// baseline (553.568 us; speedup 1.0000x reference)
//
#include <hip/hip_runtime.h>
#include <hip/hip_bf16.h>
#include <math.h>

// Problem constants
#define BB 8
#define SS 512
#define DD 768
#define LL 200

typedef __attribute__((ext_vector_type(8))) short bf16x8;
typedef __attribute__((ext_vector_type(4))) float f32x4;

__device__ inline short f2bf(float f) {
    unsigned u = __builtin_bit_cast(unsigned, f);
    unsigned r = (u + 0x7FFFu + ((u >> 16) & 1u)) >> 16;
    return (short)r;
}

#define LDP2 72    // GEMM LDS row pitch (144 B = 9*16B odd)
#define WP 168     // conv W pitch (336 B = 21*16B odd)
#define TP 24      // winT pitch (48 B)
#define WTR 217
#define WROWS 208
#define APAD 256   // K-pitch for K=200 bf16 operands
#define NBLK 96    // chain/tail grid size (<< 256 CUs -> co-resident)
#define BIGN (1 << 30)

// ---------------------------------------------------------------------------
// software grid barrier (round-8 proven): device-scope atomic + fences
// ---------------------------------------------------------------------------
__device__ inline void gbar(int* cnt, int target)
{
    __syncthreads();
    if (threadIdx.x == 0) {
        __threadfence();
        atomicAdd(cnt, 1);
        while (atomicAdd(cnt, 0) < target) __builtin_amdgcn_s_sleep(2);
        __threadfence();
    }
    __syncthreads();
}

// ---------------------------------------------------------------------------
// device GEMM: C[M,N] = epi(A_bf16[M,lda] @ B + bias)
//  BLAY: 0 = B f32 [K][ldb] (transpose-staged, coalesced reads, VECTOR writes)
//        1 = B bf16 [N][ldb] row-major (B^T, direct vector copy)
//        2 = B bf16 [K][ldb] (transpose-staged)
//  Up to 3 B-regions along N (BLAY 0/2): cols>=nsplit -> Bv2, >=nsplit2 -> Bv3
//  N must be a multiple of 64 for BLAY 0/2 (all call sites satisfy this).
// ---------------------------------------------------------------------------
template<int EPI, int BLAY>
__device__ void dev_gemm(short* As, short* Bs,
    const short* __restrict__ A, int lda,
    const void* __restrict__ Bv, int ldb,
    const float* __restrict__ bias,
    const void* __restrict__ Bv2, const float* __restrict__ bias2, int nsplit,
    const void* __restrict__ Bv3, const float* __restrict__ bias3, int nsplit2,
    float* __restrict__ Cf, int ldc,
    short* __restrict__ Cb, int ldcb,
    int M, int N, int K, int blk)
{
    const int nTiles = (N + 63) >> 6;
    const int mTiles = (M + 63) >> 6;
    if (blk >= nTiles * mTiles) return;
    const int bm = (blk / nTiles) * 64;
    const int bn = (blk % nTiles) * 64;
    int bnb = bn;
    if (BLAY != 1) {
        if (bn >= nsplit2)      { Bv = Bv3; bias = bias3; bnb = bn - nsplit2; }
        else if (bn >= nsplit)  { Bv = Bv2; bias = bias2; bnb = bn - nsplit; }
    }
    const int tid = threadIdx.x;
    const int w = tid >> 6, lane = tid & 63, g = lane >> 4, ln = lane & 15;
    const int Kp = (K + 63) & ~63;
    const int nt = Kp >> 6;

    const int ar = tid >> 2, ac = tid & 3;      // A / B(TB): row, 32B chunk
    const int bn_ = tid & 63, bko = (tid >> 6) * 16;  // B transpose-stage coords

    f32x4 acc[4];
    #pragma unroll
    for (int i = 0; i < 4; ++i) acc[i] = (f32x4){0.f, 0.f, 0.f, 0.f};

    bf16x8 aR0 = {0,0,0,0,0,0,0,0}, aR1 = {0,0,0,0,0,0,0,0};
    bf16x8 bR0 = {0,0,0,0,0,0,0,0}, bR1 = {0,0,0,0,0,0,0,0};
    short bS[16];
    #pragma unroll
    for (int j = 0; j < 16; ++j) bS[j] = 0;

    const int gmS = bm + ar;
    const bool aOk = (gmS < M);

    auto fetchA = [&](int k0) {
        if (aOk) {
            const short* p = A + (size_t)gmS * lda + k0 + ac * 16;
            aR0 = *(const bf16x8*)p;
            aR1 = *(const bf16x8*)(p + 8);
        }
    };
    auto fetchB = [&](int k0) {
        if (BLAY == 1) {
            const short* Bt = (const short*)Bv;
            int gn = bn + ar;
            if (gn < N) {
                const short* p = Bt + (size_t)gn * ldb + k0 + ac * 16;
                bR0 = *(const bf16x8*)p;
                bR1 = *(const bf16x8*)(p + 8);
            }
        } else if (BLAY == 0) {
            // thread owns column (bnb+bn_), rows k0+bko..+15; lane-coalesced
            const float* Bp = (const float*)Bv + (size_t)(bnb + bn_);
            #pragma unroll
            for (int j = 0; j < 16; ++j) {
                int gk = k0 + bko + j;                 // wave-uniform guard
                bS[j] = (gk < K) ? f2bf(Bp[(size_t)gk * ldb]) : (short)0;
            }
        } else {
            const short* Bp = (const short*)Bv + (size_t)(bnb + bn_);
            #pragma unroll
            for (int j = 0; j < 16; ++j) {
                int gk = k0 + bko + j;
                bS[j] = (gk < K) ? Bp[(size_t)gk * ldb] : (short)0;
            }
        }
    };

    fetchA(0);
    fetchB(0);

    for (int t = 0; t < nt; ++t) {
        {
            short* pa = As + ar * LDP2 + ac * 16;
            *(bf16x8*)pa = aR0;
            *(bf16x8*)(pa + 8) = aR1;
        }
        if (BLAY == 1) {
            short* pb = Bs + ar * LDP2 + ac * 16;
            *(bf16x8*)pb = bR0;
            *(bf16x8*)(pb + 8) = bR1;
        } else {
            // vector write of this thread's transposed fragment: Bs[n][k0..k0+15]
            short* pb = Bs + bn_ * LDP2 + bko;
            *(bf16x8*)pb = *(const bf16x8*)bS;
            *(bf16x8*)(pb + 8) = *(const bf16x8*)(bS + 8);
        }
        __syncthreads();

        if (t + 1 < nt) {
            int k0 = (t + 1) << 6;
            fetchA(k0);
            fetchB(k0);
        }

        #pragma unroll
        for (int ks = 0; ks < 2; ++ks) {
            bf16x8 a = *(const bf16x8*)(As + (w * 16 + ln) * LDP2 + ks * 32 + g * 8);
            #pragma unroll
            for (int nb = 0; nb < 4; ++nb) {
                bf16x8 b = *(const bf16x8*)(Bs + (nb * 16 + ln) * LDP2 + ks * 32 + g * 8);
                acc[nb] = __builtin_amdgcn_mfma_f32_16x16x32_bf16(a, b, acc[nb], 0, 0, 0);
            }
        }
        __syncthreads();
    }

    #pragma unroll
    for (int nb = 0; nb < 4; ++nb) {
        int gn = bn + nb * 16 + ln;
        float bv = (bias && gn < N) ? bias[bnb + nb * 16 + ln] : 0.f;
        #pragma unroll
        for (int r = 0; r < 4; ++r) {
            int gm = bm + w * 16 + g * 4 + r;
            if (gm < M && gn < N) {
                float v = acc[nb][r] + bv;
                if (EPI == 1) v = (v >= 0.f) ? v : 0.2f * v;
                else if (EPI == 2) v = 1.f / (1.f + expf(-v));
                if (Cf) Cf[(size_t)gm * ldc + gn] = v;
                if (Cb) Cb[(size_t)gm * ldcb + gn] = f2bf(v);
            }
        }
    }
}

#define GLOOP(tiles) for (int t = blk; t < (tiles); t += NBLK)

// ---------------------------------------------------------------------------
// chain_k: entire label-side pipeline + doc l1norm, one launch, 96 blocks
// ---------------------------------------------------------------------------
__global__ __launch_bounds__(256) void chain_k(
    const float* __restrict__ label_emb, const float* __restrict__ label_adj,
    const float* __restrict__ w_gcn3, const float* __restrict__ w_gcn5,
    const float* __restrict__ w_ll1, const float* __restrict__ b_ll1,
    const float* __restrict__ w_ll2, const float* __restrict__ b_ll2,
    const float* __restrict__ w_lin, const float* __restrict__ b_lin,
    const float* __restrict__ cw, const float* __restrict__ cb,
    const float* __restrict__ doc,
    short* wkg, short* adj_bf, short* E2_bf, short* le_cat_bf,
    short* qkh_bf, float* Amat, float* dvec, short* Anorm_bf,
    float* le_out_f, short* le_out_bf, float* denom, short* doc_nb,
    int* cnt)
{
    __shared__ __align__(16) short As[64 * LDP2];
    __shared__ __align__(16) short Bs[64 * LDP2];
    __shared__ float cred[4];
    __shared__ float dred[4][64];

    const int blk = blockIdx.x;
    const int tid = threadIdx.x;

    // S0: prep conv weights (kappa order + bias tap) and padded adjacency
    for (int idx = blk * 256 + tid; idx < WROWS * WP + LL * APAD; idx += NBLK * 256) {
        if (idx < WROWS * WP) {
            int o = idx / WP, kk = idx % WP;
            int kj = kk >> 4, ki = kk & 15;
            float v = 0.f;
            if (o < LL && kj < 9) {
                if (ki < 9) v = cw[o * 81 + ki * 9 + kj];
                else if (ki == 9 && kj == 0) v = cb[o];
            }
            wkg[idx] = f2bf(v);
        } else {
            int j2 = idx - WROWS * WP;
            int r = j2 / APAD, c = j2 % APAD;
            adj_bf[j2] = f2bf(c < LL ? label_adj[r * LL + c] : 0.f);
        }
    }
    gbar(cnt, NBLK * 1);

    // S1: E2 = adj @ emb  [200,768] K=200 (48 tiles); spare blocks: doc l1norm
    if (blk < 48) {
        GLOOP(48) dev_gemm<0, 0>(As, Bs, adj_bf, APAD, label_emb, DD, nullptr,
                                 nullptr, nullptr, BIGN, nullptr, nullptr, BIGN,
                                 nullptr, 0, E2_bf, DD, LL, DD, LL, t);
    } else {
        for (int u = blk - 48; u < 96; u += 48) {
            int bq = u / 12, dc = u % 12;
            int dx = tid & 63, sy = tid >> 6;
            int d = dc * 64 + dx;
            const float* pp = doc + (size_t)bq * SS * DD + d;
            float s = 0.f;
            for (int t2 = sy; t2 < SS; t2 += 4) s += fabsf(pp[(size_t)t2 * DD]);
            dred[sy][dx] = s;
            __syncthreads();
            float dn = fmaxf(dred[0][dx] + dred[1][dx] + dred[2][dx] + dred[3][dx], 1e-12f);
            if (sy == 0) denom[bq * DD + d] = dn;
            float inv = 1.f / dn;
            short* qq = doc_nb + (size_t)bq * SS * DD + d;
            for (int t2 = sy; t2 < SS; t2 += 4)
                qq[(size_t)t2 * DD] = f2bf(pp[(size_t)t2 * DD] * inv);
            __syncthreads();
        }
    }
    gbar(cnt, NBLK * 2);

    // S2: le = leaky(E2 @ W3) -> bf16 le_cat[:, :768]
    GLOOP(48) dev_gemm<1, 0>(As, Bs, E2_bf, DD, w_gcn3, DD, nullptr,
                             nullptr, nullptr, BIGN, nullptr, nullptr, BIGN,
                             nullptr, 0, le_cat_bf, 1536, LL, DD, DD, t);
    gbar(cnt, NBLK * 3);

    // S3: [q|k|H] = le @ [w_ll1|w_ll2|w_gcn5] + [b1|b2|0]  N=2304 (144 tiles)
    GLOOP(144) dev_gemm<0, 0>(As, Bs, le_cat_bf, 1536, w_ll1, DD, b_ll1,
                              w_ll2, b_ll2, DD, w_gcn5, nullptr, 2 * DD,
                              nullptr, 0, qkh_bf, 2304, LL, 3 * DD, DD, t);
    gbar(cnt, NBLK * 4);

    // S4: A = sigmoid(q @ k^T)  [200,200] K=768 (16 tiles)
    GLOOP(16) dev_gemm<2, 1>(As, Bs, qkh_bf, 2304, qkh_bf + DD, 2304, nullptr,
                             nullptr, nullptr, BIGN, nullptr, nullptr, BIGN,
                             Amat, LL, nullptr, 0, LL, LL, DD, t);
    gbar(cnt, NBLK * 5);

    // S5a: dvec[j] = rsqrt(colsum_j(A))
    for (int j = blk; j < LL; j += NBLK) {
        float s = (tid < LL) ? Amat[tid * LL + j] : 0.f;
        #pragma unroll
        for (int off = 32; off > 0; off >>= 1) s += __shfl_down(s, off, 64);
        if ((tid & 63) == 0) cred[tid >> 6] = s;
        __syncthreads();
        if (tid == 0) {
            float t = cred[0] + cred[1] + cred[2] + cred[3];
            dvec[j] = (t > 0.f) ? (1.f / sqrtf(t)) : 0.f;
        }
        __syncthreads();
    }
    gbar(cnt, NBLK * 6);

    // S5b: Anorm[i][j] = bf16(A[j,i] * d[i] * d[j]), padded APAD
    for (int idx = blk * 256 + tid; idx < LL * APAD; idx += NBLK * 256) {
        int i = idx / APAD, j = idx % APAD;
        float v = (j < LL) ? Amat[j * LL + i] * dvec[i] * dvec[j] : 0.f;
        Anorm_bf[idx] = f2bf(v);
    }
    gbar(cnt, NBLK * 7);

    // S6: d_le = leaky(Anorm @ H)  K=200 (48 tiles) -> le_cat[:, 768:]
    GLOOP(48) dev_gemm<1, 2>(As, Bs, Anorm_bf, APAD, qkh_bf + 2 * DD, 2304, nullptr,
                             nullptr, nullptr, BIGN, nullptr, nullptr, BIGN,
                             nullptr, 0, le_cat_bf + DD, 1536, LL, DD, LL, t);
    gbar(cnt, NBLK * 8);

    // S7: le_out = le_cat @ w_lin + b_lin  K=1536 (48 tiles)
    GLOOP(48) dev_gemm<0, 0>(As, Bs, le_cat_bf, 1536, w_lin, DD, b_lin,
                             nullptr, nullptr, BIGN, nullptr, nullptr, BIGN,
                             le_out_f, DD, nullptr, 0, LL, DD, 2 * DD, t);
    gbar(cnt, NBLK * 9);

    // S8: l1-normalize le_out over L (block = 8 cols x 32 lanes)
    {
        int c = tid >> 5, r = tid & 31;
        int col = blk * 8 + c;                 // 96*8 = 768
        float s = 0.f;
        for (int l = r; l < LL; l += 32) s += fabsf(le_out_f[l * DD + col]);
        #pragma unroll
        for (int off = 16; off > 0; off >>= 1) s += __shfl_xor(s, off, 64);
        float inv = 1.f / fmaxf(s, 1e-12f);
        for (int l = r; l < LL; l += 32)
            le_out_bf[l * DD + col] = f2bf(le_out_f[l * DD + col] * inv);
    }
}

// ---------------------------------------------------------------------------
// wla = doc_n @ le_out^T   [4096,200] K=768  (256 tiles, own launch)
// ---------------------------------------------------------------------------
__global__ __launch_bounds__(256) void wla_k(const short* __restrict__ doc_nb,
                                             const short* __restrict__ le_out_bf,
                                             float* __restrict__ wla)
{
    __shared__ __align__(16) short As[64 * LDP2];
    __shared__ __align__(16) short Bs[64 * LDP2];
    dev_gemm<0, 1>(As, Bs, doc_nb, DD, le_out_bf, DD, nullptr,
                   nullptr, nullptr, BIGN, nullptr, nullptr, BIGN,
                   wla, LL, nullptr, 0, BB * SS, LL, DD, blockIdx.x);
}

// ---------------------------------------------------------------------------
// conv kernel — UNCHANGED (verified, 62 us)
// ---------------------------------------------------------------------------
__global__ __launch_bounds__(512, 1) void conv_max_k(
    const float* __restrict__ wla,
    const short* __restrict__ wkg,
    float* __restrict__ gate)
{
    extern __shared__ short smem[];
    short* Wk   = smem;
    short* winT = Wk + WROWS * WP;
    short* wbf  = winT + 4 * WTR * TP;
    __shared__ float wredf[8];

    const int blk = blockIdx.x;
    const int b = blk >> 7;
    const int s0 = (blk & 127) << 2;
    const int tid = threadIdx.x;

    {
        const int4* src = (const int4*)wkg;
        int4* dst = (int4*)Wk;
        for (int i = tid; i < WROWS * WP / 8; i += 512) dst[i] = src[i];
    }
    for (int idx = tid; idx < 12 * 216; idx += 512) {
        int r = idx / 216, c = idx % 216;
        int sr = s0 - 4 + r, col = c - 4;
        float v = 0.f;
        if (sr >= 0 && sr < SS && col >= 0 && col < LL)
            v = wla[((size_t)b * SS + sr) * LL + col];
        wbf[idx] = f2bf(v);
    }
    __syncthreads();
    for (int idx = tid; idx < 4 * WTR; idx += 512) {
        int p = idx / WTR, r = idx % WTR;
        short vals[16];
        #pragma unroll
        for (int i = 0; i < 9; ++i) vals[i] = (r < 216) ? wbf[(p + i) * 216 + r] : (short)0;
        vals[9] = (short)0x3F80;
        #pragma unroll
        for (int i = 10; i < 16; ++i) vals[i] = 0;
        short* dstp = winT + (p * WTR + r) * TP;
        *(bf16x8*)dstp = *(const bf16x8*)vals;
        *(bf16x8*)(dstp + 8) = *(const bf16x8*)(vals + 8);
    }
    __syncthreads();

    const int w = tid >> 6;
    const int p = w >> 1;
    const int h = w & 1;
    const int lane = tid & 63;
    const int g = lane >> 4;
    const int ln = lane & 15;
    const short* WT = winT + p * WTR * TP;

    bf16x8 Af[7][5];
    #pragma unroll
    for (int s = 0; s < 7; ++s) {
        int st = h * 7 + s;
        if (st > 12) st = 12;
        #pragma unroll
        for (int j = 0; j < 5; ++j)
            Af[s][j] = *(const bf16x8*)(Wk + (st * 16 + ln) * WP + j * 32 + g * 8);
    }

    float lm = -INFINITY;

    auto loadB = [&](int nt, bf16x8 (&Bf)[5]) {
        #pragma unroll
        for (int j = 0; j < 5; ++j)
            Bf[j] = *(const bf16x8*)(WT + (nt * 16 + ln + 2 * j + (g >> 1)) * TP + (g & 1) * 8);
    };
    auto compute = [&](int nt, const bf16x8 (&Bf)[5]) {
        #pragma unroll
        for (int s = 0; s < 7; ++s) {
            if (h == 0 || s < 6) {
                int st = h * 7 + s;
                f32x4 acc = {0.f, 0.f, 0.f, 0.f};
                #pragma unroll
                for (int j = 0; j < 5; ++j)
                    acc = __builtin_amdgcn_mfma_f32_16x16x32_bf16(Af[s][j], Bf[j], acc, 0, 0, 0);
                float t = fmaxf(fmaxf(acc[0], acc[1]), fmaxf(acc[2], acc[3]));
                bool ok = (st < 12 || g < 2) && (nt < 12 || ln < 8);
                lm = ok ? fmaxf(lm, t) : lm;
            }
        }
    };

    bf16x8 B0[5], B1[5];
    loadB(0, B0);
    for (int nt = 0; nt < 12; nt += 2) {
        loadB(nt + 1, B1);
        compute(nt, B0);
        loadB(nt + 2, B0);
        compute(nt + 1, B1);
    }
    compute(12, B0);

    #pragma unroll
    for (int off = 32; off > 0; off >>= 1)
        lm = fmaxf(lm, __shfl_xor(lm, off, 64));
    if (lane == 0) wredf[w] = lm;
    __syncthreads();
    if (tid < 4)
        gate[((size_t)b << 9) + s0 + tid] = tanhf(fmaxf(wredf[2 * tid], wredf[2 * tid + 1]));
}

// ---------------------------------------------------------------------------
// tail_k: henc partials -> barrier -> final linear+sigmoid -> barrier -> loss
// ---------------------------------------------------------------------------
__global__ __launch_bounds__(256) void tail_k(
    const float* __restrict__ doc, const float* __restrict__ gate,
    const float* __restrict__ denom, const float* __restrict__ W,
    const float* __restrict__ bias, const float* __restrict__ labels,
    float* hpart, float* out, int* cnt)
{
    __shared__ float red[4][64];
    __shared__ float hb[DD];
    __shared__ float ws4[4];
    const int blk = blockIdx.x;
    const int tid = threadIdx.x;

    for (int u = blk; u < 768; u += NBLK) {
        int dc = u % 12, sc = (u / 12) % 8, b = u / 96;
        int dx = tid & 63, sy = tid >> 6;
        int d = dc * 64 + dx;
        float s = 0.f;
        for (int t = sy; t < 64; t += 4) {
            int srow = sc * 64 + t;
            s = fmaf(doc[((size_t)b * SS + srow) * DD + d], gate[b * SS + srow], s);
        }
        red[sy][dx] = s;
        __syncthreads();
        if (sy == 0)
            hpart[((size_t)b * 8 + sc) * DD + d] = red[0][dx] + red[1][dx] + red[2][dx] + red[3][dx];
        __syncthreads();
    }
    gbar(cnt, NBLK * 1);

    if (blk < BB) {
        int b = blk;
        for (int idx = tid; idx < DD; idx += 256) {
            float s = 0.f;
            #pragma unroll
            for (int sc = 0; sc < 8; ++sc) s += hpart[((size_t)b * 8 + sc) * DD + idx];
            hb[idx] = s / denom[b * DD + idx];
        }
        __syncthreads();
        int l = tid;
        if (l < LL) {
            float acc = bias[l];
            for (int d = 0; d < DD; ++d) acc = fmaf(hb[d], W[d * LL + l], acc);
            out[b * LL + l] = 1.f / (1.f + expf(-acc));
        }
    }
    gbar(cnt, NBLK * 2);

    if (blk == 0) {
        float s = 0.f;
        for (int i = tid; i < BB * LL; i += 256) {
            float p = out[i];
            p = fminf(fmaxf(p, 1e-7f), 1.f - 1e-7f);
            float y = labels[i];
            s += y * logf(p) + (1.f - y) * logf(1.f - p);
        }
        #pragma unroll
        for (int off = 32; off > 0; off >>= 1) s += __shfl_down(s, off, 64);
        if ((tid & 63) == 0) ws4[tid >> 6] = s;
        __syncthreads();
        if (tid == 0)
            out[BB * LL] = -(ws4[0] + ws4[1] + ws4[2] + ws4[3]) / (float)(BB * LL);
    }
}

// ---------------------------------------------------------------------------
extern "C" void kernel_launch(void* const* d_in, const int* in_sizes, int n_in,
                              void* d_out, int out_size, void* d_ws, size_t ws_size,
                              hipStream_t stream)
{
    const float* doc_emb   = (const float*)d_in[0];
    const float* labels    = (const float*)d_in[1];
    const float* label_emb = (const float*)d_in[2];
    const float* label_adj = (const float*)d_in[3];
    const float* w_gcn3    = (const float*)d_in[4];
    const float* w_gcn5    = (const float*)d_in[5];
    const float* w_ll1     = (const float*)d_in[6];
    const float* b_ll1     = (const float*)d_in[7];
    const float* w_ll2     = (const float*)d_in[8];
    const float* b_ll2     = (const float*)d_in[9];
    const float* w_lin     = (const float*)d_in[10];
    const float* b_lin     = (const float*)d_in[11];
    const float* conv_w    = (const float*)d_in[12];
    const float* conv_b    = (const float*)d_in[13];
    const float* w_lin1    = (const float*)d_in[14];
    const float* b_lin1    = (const float*)d_in[15];

    float* out = (float*)d_out;   // [B*L] + [1]

    char* p = (char*)d_ws;
    auto alloc = [&](size_t bytes) { void* r = p; p += (bytes + 15) & ~(size_t)15; return r; };
    int*   cnt       = (int*)alloc(16);
    short* wkg       = (short*)alloc(WROWS * WP * 2);
    short* adj_bf    = (short*)alloc(200 * APAD * 2);
    short* E2_bf     = (short*)alloc(200 * 768 * 2);
    short* le_cat_bf = (short*)alloc(200 * 1536 * 2);
    short* qkh_bf    = (short*)alloc(200 * 2304 * 2);
    float* Amat      = (float*)alloc(200 * 200 * 4);
    float* dvec      = (float*)alloc(256 * 4);
    short* Anorm_bf  = (short*)alloc(200 * APAD * 2);
    float* le_out_f  = (float*)alloc(200 * 768 * 4);
    short* le_out_bf = (short*)alloc(200 * 768 * 2);
    float* denom     = (float*)alloc(BB * DD * 4);
    short* doc_nb    = (short*)alloc((size_t)BB * SS * DD * 2);
    float* wla       = (float*)alloc((size_t)BB * SS * LL * 4);
    float* gatev     = (float*)alloc(BB * SS * 4);
    float* hpart     = (float*)alloc(BB * 8 * DD * 4);

    hipMemsetAsync(cnt, 0, 16, stream);

    chain_k<<<NBLK, 256, 0, stream>>>(
        label_emb, label_adj, w_gcn3, w_gcn5, w_ll1, b_ll1, w_ll2, b_ll2,
        w_lin, b_lin, conv_w, conv_b, doc_emb,
        wkg, adj_bf, E2_bf, le_cat_bf, qkh_bf, Amat, dvec, Anorm_bf,
        le_out_f, le_out_bf, denom, doc_nb, cnt);

    wla_k<<<256, 256, 0, stream>>>(doc_nb, le_out_bf, wla);

    (void)hipFuncSetAttribute((const void*)conv_max_k,
                              hipFuncAttributeMaxDynamicSharedMemorySize, 116736);
    conv_max_k<<<1024, 512, 116736, stream>>>(wla, wkg, gatev);

    tail_k<<<NBLK, 256, 0, stream>>>(doc_emb, gatev, denom, w_lin1, b_lin1,
                                     labels, hpart, out, cnt + 1);
}

// Round 10
// 550.295 us; speedup vs baseline: 1.0059x; 1.0059x over previous
//
#include <hip/hip_runtime.h>
#include <hip/hip_bf16.h>
#include <math.h>

// Problem constants
#define BB 8
#define SS 512
#define DD 768
#define LL 200

typedef __attribute__((ext_vector_type(8))) short bf16x8;
typedef __attribute__((ext_vector_type(4))) float f32x4;

__device__ inline short f2bf(float f) {
    unsigned u = __builtin_bit_cast(unsigned, f);
    unsigned r = (u + 0x7FFFu + ((u >> 16) & 1u)) >> 16;
    return (short)r;
}

#define LDP2 72    // GEMM LDS row pitch (144 B = 9*16B odd)
#define WP 168     // conv W pitch (336 B = 21*16B odd)
#define TP 24      // winT pitch (48 B)
#define WTR 217
#define WROWS 208
#define APAD 256   // K-pitch for K=200 bf16 operands
#define NBLK 96    // chain/tail grid size (co-resident on 256 CUs)
#define BIGN (1 << 30)

// ---------------------------------------------------------------------------
// software grid barrier: arrival = device-scope RMW (proven R8), poll = relaxed
// agent-scope LOAD (no RMW serialization at the coherence point).
// ---------------------------------------------------------------------------
__device__ inline void gbar(int* cnt, int target)
{
    __syncthreads();
    if (threadIdx.x == 0) {
        __threadfence();
        atomicAdd(cnt, 1);
        while (__hip_atomic_load(cnt, __ATOMIC_RELAXED, __HIP_MEMORY_SCOPE_AGENT) < target)
            __builtin_amdgcn_s_sleep(2);
        __threadfence();
    }
    __syncthreads();
}

// ---------------------------------------------------------------------------
// device GEMM: C[M,N] = epi(A_bf16[M,lda] @ B + bias)
//  BLAY: 0 = B f32 [K][ldb]  (per-thread column fetch, REGISTER transpose,
//                             vector LDS writes — no scratch, no scalar writes)
//        1 = B bf16 [N][ldb] row-major (B^T, direct vector copy)
//        2 = B bf16 [K][ldb] (register transpose, as BLAY 0)
//  Up to 3 B-regions along N (BLAY 0/2); N multiple of 64 at those call sites.
// ---------------------------------------------------------------------------
template<int EPI, int BLAY>
__device__ void dev_gemm(short* As, short* Bs,
    const short* __restrict__ A, int lda,
    const void* __restrict__ Bv, int ldb,
    const float* __restrict__ bias,
    const void* __restrict__ Bv2, const float* __restrict__ bias2, int nsplit,
    const void* __restrict__ Bv3, const float* __restrict__ bias3, int nsplit2,
    float* __restrict__ Cf, int ldc,
    short* __restrict__ Cb, int ldcb,
    int M, int N, int K, int blk)
{
    const int nTiles = (N + 63) >> 6;
    const int mTiles = (M + 63) >> 6;
    if (blk >= nTiles * mTiles) return;
    const int bm = (blk / nTiles) * 64;
    const int bn = (blk % nTiles) * 64;
    int bnb = bn;
    if (BLAY != 1) {
        if (bn >= nsplit2)      { Bv = Bv3; bias = bias3; bnb = bn - nsplit2; }
        else if (bn >= nsplit)  { Bv = Bv2; bias = bias2; bnb = bn - nsplit; }
    }
    const int tid = threadIdx.x;
    const int w = tid >> 6, lane = tid & 63, g = lane >> 4, ln = lane & 15;
    const int Kp = (K + 63) & ~63;
    const int nt = Kp >> 6;

    const int ar = tid >> 2, ac = tid & 3;            // A / B(BLAY1) staging
    const int bn_ = tid & 63, bko = (tid >> 6) * 16;  // B transpose staging

    f32x4 acc[4];
    #pragma unroll
    for (int i = 0; i < 4; ++i) acc[i] = (f32x4){0.f, 0.f, 0.f, 0.f};

    bf16x8 aR0 = {0,0,0,0,0,0,0,0}, aR1 = {0,0,0,0,0,0,0,0};
    bf16x8 bR0 = {0,0,0,0,0,0,0,0}, bR1 = {0,0,0,0,0,0,0,0};

    const int gmS = bm + ar;
    const bool aOk = (gmS < M);

    auto fetchA = [&](int k0) {
        if (aOk) {
            const short* p = A + (size_t)gmS * lda + k0 + ac * 16;
            aR0 = *(const bf16x8*)p;
            aR1 = *(const bf16x8*)(p + 8);
        }
    };
    auto fetchB = [&](int k0) {
        if (BLAY == 1) {
            const short* Bt = (const short*)Bv;
            int gn = bn + ar;
            if (gn < N) {
                const short* p = Bt + (size_t)gn * ldb + k0 + ac * 16;
                bR0 = *(const bf16x8*)p;
                bR1 = *(const bf16x8*)(p + 8);
            }
        } else if (BLAY == 0) {
            // thread owns column (bnb+bn_); lanes consecutive -> coalesced
            const float* Bp = (const float*)Bv + (size_t)(bnb + bn_);
            #pragma unroll
            for (int j = 0; j < 8; ++j) {
                int gk = k0 + bko + j;                 // wave-uniform guard
                bR0[j] = (gk < K) ? f2bf(Bp[(size_t)gk * ldb]) : (short)0;
            }
            #pragma unroll
            for (int j = 0; j < 8; ++j) {
                int gk = k0 + bko + 8 + j;
                bR1[j] = (gk < K) ? f2bf(Bp[(size_t)gk * ldb]) : (short)0;
            }
        } else {
            const short* Bp = (const short*)Bv + (size_t)(bnb + bn_);
            #pragma unroll
            for (int j = 0; j < 8; ++j) {
                int gk = k0 + bko + j;
                bR0[j] = (gk < K) ? Bp[(size_t)gk * ldb] : (short)0;
            }
            #pragma unroll
            for (int j = 0; j < 8; ++j) {
                int gk = k0 + bko + 8 + j;
                bR1[j] = (gk < K) ? Bp[(size_t)gk * ldb] : (short)0;
            }
        }
    };

    fetchA(0);
    fetchB(0);

    for (int t = 0; t < nt; ++t) {
        {
            short* pa = As + ar * LDP2 + ac * 16;
            *(bf16x8*)pa = aR0;
            *(bf16x8*)(pa + 8) = aR1;
        }
        if (BLAY == 1) {
            short* pb = Bs + ar * LDP2 + ac * 16;
            *(bf16x8*)pb = bR0;
            *(bf16x8*)(pb + 8) = bR1;
        } else {
            // vector writes of transposed fragment: Bs[n][bko..bko+15]
            short* pb = Bs + bn_ * LDP2 + bko;
            *(bf16x8*)pb = bR0;
            *(bf16x8*)(pb + 8) = bR1;
        }
        __syncthreads();

        if (t + 1 < nt) {
            int k0 = (t + 1) << 6;
            fetchA(k0);
            fetchB(k0);
        }

        #pragma unroll
        for (int ks = 0; ks < 2; ++ks) {
            bf16x8 a = *(const bf16x8*)(As + (w * 16 + ln) * LDP2 + ks * 32 + g * 8);
            #pragma unroll
            for (int nb = 0; nb < 4; ++nb) {
                bf16x8 b = *(const bf16x8*)(Bs + (nb * 16 + ln) * LDP2 + ks * 32 + g * 8);
                acc[nb] = __builtin_amdgcn_mfma_f32_16x16x32_bf16(a, b, acc[nb], 0, 0, 0);
            }
        }
        __syncthreads();
    }

    #pragma unroll
    for (int nb = 0; nb < 4; ++nb) {
        int gn = bn + nb * 16 + ln;
        float bv = (bias && gn < N) ? bias[bnb + nb * 16 + ln] : 0.f;
        #pragma unroll
        for (int r = 0; r < 4; ++r) {
            int gm = bm + w * 16 + g * 4 + r;
            if (gm < M && gn < N) {
                float v = acc[nb][r] + bv;
                if (EPI == 1) v = (v >= 0.f) ? v : 0.2f * v;
                else if (EPI == 2) v = 1.f / (1.f + expf(-v));
                if (Cf) Cf[(size_t)gm * ldc + gn] = v;
                if (Cb) Cb[(size_t)gm * ldcb + gn] = f2bf(v);
            }
        }
    }
}

#define GLOOP(tiles) for (int t = blk; t < (tiles); t += NBLK)

// ---------------------------------------------------------------------------
// chain_k: entire label-side pipeline + doc l1norm; 96 blocks, 8 grid barriers
// ---------------------------------------------------------------------------
__global__ __launch_bounds__(256) void chain_k(
    const float* __restrict__ label_emb, const float* __restrict__ label_adj,
    const float* __restrict__ w_gcn3, const float* __restrict__ w_gcn5,
    const float* __restrict__ w_ll1, const float* __restrict__ b_ll1,
    const float* __restrict__ w_ll2, const float* __restrict__ b_ll2,
    const float* __restrict__ w_lin, const float* __restrict__ b_lin,
    const float* __restrict__ cw, const float* __restrict__ cb,
    const float* __restrict__ doc,
    short* wkg, short* adj_bf, short* E2_bf, short* le_cat_bf,
    short* qkh_bf, float* Amat, short* Anorm_bf,
    float* le_out_f, short* le_out_bf, float* denom, short* doc_nb,
    int* cnt)
{
    __shared__ __align__(16) short As[64 * LDP2];
    __shared__ __align__(16) short Bs[64 * LDP2];
    __shared__ float dv[256];
    __shared__ float dred[4][64];

    const int blk = blockIdx.x;
    const int tid = threadIdx.x;

    // P0: prep conv weights (kappa order + bias tap) and padded adjacency
    for (int idx = blk * 256 + tid; idx < WROWS * WP + LL * APAD; idx += NBLK * 256) {
        if (idx < WROWS * WP) {
            int o = idx / WP, kk = idx % WP;
            int kj = kk >> 4, ki = kk & 15;
            float v = 0.f;
            if (o < LL && kj < 9) {
                if (ki < 9) v = cw[o * 81 + ki * 9 + kj];
                else if (ki == 9 && kj == 0) v = cb[o];
            }
            wkg[idx] = f2bf(v);
        } else {
            int j2 = idx - WROWS * WP;
            int r = j2 / APAD, c = j2 % APAD;
            adj_bf[j2] = f2bf(c < LL ? label_adj[r * LL + c] : 0.f);
        }
    }
    gbar(cnt, NBLK * 1);

    // P1: E2 = adj @ emb  [200,768] K=200 (48 tiles)
    GLOOP(48) dev_gemm<0, 0>(As, Bs, adj_bf, APAD, label_emb, DD, nullptr,
                             nullptr, nullptr, BIGN, nullptr, nullptr, BIGN,
                             nullptr, 0, E2_bf, DD, LL, DD, LL, t);
    gbar(cnt, NBLK * 2);

    // P2: le = leaky(E2 @ W3) -> bf16 le_cat[:, :768]
    GLOOP(48) dev_gemm<1, 0>(As, Bs, E2_bf, DD, w_gcn3, DD, nullptr,
                             nullptr, nullptr, BIGN, nullptr, nullptr, BIGN,
                             nullptr, 0, le_cat_bf, 1536, LL, DD, DD, t);
    gbar(cnt, NBLK * 3);

    // P3: [q|k|H] = le @ [w_ll1|w_ll2|w_gcn5] + [b1|b2|0]  N=2304 (144 tiles)
    GLOOP(144) dev_gemm<0, 0>(As, Bs, le_cat_bf, 1536, w_ll1, DD, b_ll1,
                              w_ll2, b_ll2, DD, w_gcn5, nullptr, 2 * DD,
                              nullptr, 0, qkh_bf, 2304, LL, 3 * DD, DD, t);
    gbar(cnt, NBLK * 4);

    // P4: A = sigmoid(q @ k^T)  [200,200] K=768 (16 tiles)
    GLOOP(16) dev_gemm<2, 1>(As, Bs, qkh_bf, 2304, qkh_bf + DD, 2304, nullptr,
                             nullptr, nullptr, BIGN, nullptr, nullptr, BIGN,
                             Amat, LL, nullptr, 0, LL, LL, DD, t);
    gbar(cnt, NBLK * 5);

    // P5: dvec (redundant per block, into LDS) + Anorm write (merged stage)
    {
        float s = 0.f;
        if (tid < LL)
            for (int l = 0; l < LL; ++l) s += Amat[l * LL + tid];
        dv[tid] = (tid < LL && s > 0.f) ? (1.f / sqrtf(s)) : 0.f;
        __syncthreads();
        for (int idx = blk * 256 + tid; idx < LL * APAD; idx += NBLK * 256) {
            int i = idx / APAD, j = idx % APAD;
            float v = (j < LL) ? Amat[j * LL + i] * dv[i] * dv[j] : 0.f;
            Anorm_bf[idx] = f2bf(v);
        }
    }
    gbar(cnt, NBLK * 6);

    // P6: d_le = leaky(Anorm @ H)  K=200 (48 tiles) -> le_cat[:, 768:]
    GLOOP(48) dev_gemm<1, 2>(As, Bs, Anorm_bf, APAD, qkh_bf + 2 * DD, 2304, nullptr,
                             nullptr, nullptr, BIGN, nullptr, nullptr, BIGN,
                             nullptr, 0, le_cat_bf + DD, 1536, LL, DD, LL, t);
    gbar(cnt, NBLK * 7);

    // P7: le_out = le_cat @ w_lin + b_lin  K=1536 (48 tiles)
    GLOOP(48) dev_gemm<0, 0>(As, Bs, le_cat_bf, 1536, w_lin, DD, b_lin,
                             nullptr, nullptr, BIGN, nullptr, nullptr, BIGN,
                             le_out_f, DD, nullptr, 0, LL, DD, 2 * DD, t);
    gbar(cnt, NBLK * 8);

    // P8a: l1-normalize le_out over L (block = 8 cols x 32 lanes)
    {
        int c = tid >> 5, r = tid & 31;
        int col = blk * 8 + c;                 // 96*8 = 768
        float s = 0.f;
        for (int l = r; l < LL; l += 32) s += fabsf(le_out_f[l * DD + col]);
        #pragma unroll
        for (int off = 16; off > 0; off >>= 1) s += __shfl_xor(s, off, 64);
        float inv = 1.f / fmaxf(s, 1e-12f);
        for (int l = r; l < LL; l += 32)
            le_out_bf[l * DD + col] = f2bf(le_out_f[l * DD + col] * inv);
    }

    // P8b: doc l1norm (self-contained per block; no barrier - kernel boundary)
    {
        int bq = blk / 12, dc = blk % 12;
        int dx = tid & 63, sy = tid >> 6;
        int d = dc * 64 + dx;
        const float* pp = doc + (size_t)bq * SS * DD + d;
        float s = 0.f;
        for (int t2 = sy; t2 < SS; t2 += 4) s += fabsf(pp[(size_t)t2 * DD]);
        dred[sy][dx] = s;
        __syncthreads();
        float dn = fmaxf(dred[0][dx] + dred[1][dx] + dred[2][dx] + dred[3][dx], 1e-12f);
        if (sy == 0) denom[bq * DD + d] = dn;
        float inv = 1.f / dn;
        short* qq = doc_nb + (size_t)bq * SS * DD + d;
        for (int t2 = sy; t2 < SS; t2 += 4)
            qq[(size_t)t2 * DD] = f2bf(pp[(size_t)t2 * DD] * inv);
    }
}

// ---------------------------------------------------------------------------
// wla = doc_n @ le_out^T   [4096,200] K=768  (256 tiles, own launch)
// ---------------------------------------------------------------------------
__global__ __launch_bounds__(256) void wla_k(const short* __restrict__ doc_nb,
                                             const short* __restrict__ le_out_bf,
                                             float* __restrict__ wla)
{
    __shared__ __align__(16) short As[64 * LDP2];
    __shared__ __align__(16) short Bs[64 * LDP2];
    dev_gemm<0, 1>(As, Bs, doc_nb, DD, le_out_bf, DD, nullptr,
                   nullptr, nullptr, BIGN, nullptr, nullptr, BIGN,
                   wla, LL, nullptr, 0, BB * SS, LL, DD, blockIdx.x);
}

// ---------------------------------------------------------------------------
// conv kernel — UNCHANGED (verified, 62 us)
// ---------------------------------------------------------------------------
__global__ __launch_bounds__(512, 1) void conv_max_k(
    const float* __restrict__ wla,
    const short* __restrict__ wkg,
    float* __restrict__ gate)
{
    extern __shared__ short smem[];
    short* Wk   = smem;
    short* winT = Wk + WROWS * WP;
    short* wbf  = winT + 4 * WTR * TP;
    __shared__ float wredf[8];

    const int blk = blockIdx.x;
    const int b = blk >> 7;
    const int s0 = (blk & 127) << 2;
    const int tid = threadIdx.x;

    {
        const int4* src = (const int4*)wkg;
        int4* dst = (int4*)Wk;
        for (int i = tid; i < WROWS * WP / 8; i += 512) dst[i] = src[i];
    }
    for (int idx = tid; idx < 12 * 216; idx += 512) {
        int r = idx / 216, c = idx % 216;
        int sr = s0 - 4 + r, col = c - 4;
        float v = 0.f;
        if (sr >= 0 && sr < SS && col >= 0 && col < LL)
            v = wla[((size_t)b * SS + sr) * LL + col];
        wbf[idx] = f2bf(v);
    }
    __syncthreads();
    for (int idx = tid; idx < 4 * WTR; idx += 512) {
        int p = idx / WTR, r = idx % WTR;
        short vals[16];
        #pragma unroll
        for (int i = 0; i < 9; ++i) vals[i] = (r < 216) ? wbf[(p + i) * 216 + r] : (short)0;
        vals[9] = (short)0x3F80;
        #pragma unroll
        for (int i = 10; i < 16; ++i) vals[i] = 0;
        short* dstp = winT + (p * WTR + r) * TP;
        *(bf16x8*)dstp = *(const bf16x8*)vals;
        *(bf16x8*)(dstp + 8) = *(const bf16x8*)(vals + 8);
    }
    __syncthreads();

    const int w = tid >> 6;
    const int p = w >> 1;
    const int h = w & 1;
    const int lane = tid & 63;
    const int g = lane >> 4;
    const int ln = lane & 15;
    const short* WT = winT + p * WTR * TP;

    bf16x8 Af[7][5];
    #pragma unroll
    for (int s = 0; s < 7; ++s) {
        int st = h * 7 + s;
        if (st > 12) st = 12;
        #pragma unroll
        for (int j = 0; j < 5; ++j)
            Af[s][j] = *(const bf16x8*)(Wk + (st * 16 + ln) * WP + j * 32 + g * 8);
    }

    float lm = -INFINITY;

    auto loadB = [&](int nt, bf16x8 (&Bf)[5]) {
        #pragma unroll
        for (int j = 0; j < 5; ++j)
            Bf[j] = *(const bf16x8*)(WT + (nt * 16 + ln + 2 * j + (g >> 1)) * TP + (g & 1) * 8);
    };
    auto compute = [&](int nt, const bf16x8 (&Bf)[5]) {
        #pragma unroll
        for (int s = 0; s < 7; ++s) {
            if (h == 0 || s < 6) {
                int st = h * 7 + s;
                f32x4 acc = {0.f, 0.f, 0.f, 0.f};
                #pragma unroll
                for (int j = 0; j < 5; ++j)
                    acc = __builtin_amdgcn_mfma_f32_16x16x32_bf16(Af[s][j], Bf[j], acc, 0, 0, 0);
                float t = fmaxf(fmaxf(acc[0], acc[1]), fmaxf(acc[2], acc[3]));
                bool ok = (st < 12 || g < 2) && (nt < 12 || ln < 8);
                lm = ok ? fmaxf(lm, t) : lm;
            }
        }
    };

    bf16x8 B0[5], B1[5];
    loadB(0, B0);
    for (int nt = 0; nt < 12; nt += 2) {
        loadB(nt + 1, B1);
        compute(nt, B0);
        loadB(nt + 2, B0);
        compute(nt + 1, B1);
    }
    compute(12, B0);

    #pragma unroll
    for (int off = 32; off > 0; off >>= 1)
        lm = fmaxf(lm, __shfl_xor(lm, off, 64));
    if (lane == 0) wredf[w] = lm;
    __syncthreads();
    if (tid < 4)
        gate[((size_t)b << 9) + s0 + tid] = tanhf(fmaxf(wredf[2 * tid], wredf[2 * tid + 1]));
}

// ---------------------------------------------------------------------------
// tail_k: henc partials -> barrier -> final linear+sigmoid -> barrier -> loss
// ---------------------------------------------------------------------------
__global__ __launch_bounds__(256) void tail_k(
    const float* __restrict__ doc, const float* __restrict__ gate,
    const float* __restrict__ denom, const float* __restrict__ W,
    const float* __restrict__ bias, const float* __restrict__ labels,
    float* hpart, float* out, int* cnt)
{
    __shared__ float red[4][64];
    __shared__ float hb[DD];
    __shared__ float ws4[4];
    const int blk = blockIdx.x;
    const int tid = threadIdx.x;

    for (int u = blk; u < 768; u += NBLK) {
        int dc = u % 12, sc = (u / 12) % 8, b = u / 96;
        int dx = tid & 63, sy = tid >> 6;
        int d = dc * 64 + dx;
        float s = 0.f;
        for (int t = sy; t < 64; t += 4) {
            int srow = sc * 64 + t;
            s = fmaf(doc[((size_t)b * SS + srow) * DD + d], gate[b * SS + srow], s);
        }
        red[sy][dx] = s;
        __syncthreads();
        if (sy == 0)
            hpart[((size_t)b * 8 + sc) * DD + d] = red[0][dx] + red[1][dx] + red[2][dx] + red[3][dx];
        __syncthreads();
    }
    gbar(cnt, NBLK * 1);

    if (blk < BB) {
        int b = blk;
        for (int idx = tid; idx < DD; idx += 256) {
            float s = 0.f;
            #pragma unroll
            for (int sc = 0; sc < 8; ++sc) s += hpart[((size_t)b * 8 + sc) * DD + idx];
            hb[idx] = s / denom[b * DD + idx];
        }
        __syncthreads();
        int l = tid;
        if (l < LL) {
            float acc = bias[l];
            for (int d = 0; d < DD; ++d) acc = fmaf(hb[d], W[d * LL + l], acc);
            out[b * LL + l] = 1.f / (1.f + expf(-acc));
        }
    }
    gbar(cnt, NBLK * 2);

    if (blk == 0) {
        float s = 0.f;
        for (int i = tid; i < BB * LL; i += 256) {
            float p = out[i];
            p = fminf(fmaxf(p, 1e-7f), 1.f - 1e-7f);
            float y = labels[i];
            s += y * logf(p) + (1.f - y) * logf(1.f - p);
        }
        #pragma unroll
        for (int off = 32; off > 0; off >>= 1) s += __shfl_down(s, off, 64);
        if ((tid & 63) == 0) ws4[tid >> 6] = s;
        __syncthreads();
        if (tid == 0)
            out[BB * LL] = -(ws4[0] + ws4[1] + ws4[2] + ws4[3]) / (float)(BB * LL);
    }
}

// ---------------------------------------------------------------------------
extern "C" void kernel_launch(void* const* d_in, const int* in_sizes, int n_in,
                              void* d_out, int out_size, void* d_ws, size_t ws_size,
                              hipStream_t stream)
{
    const float* doc_emb   = (const float*)d_in[0];
    const float* labels    = (const float*)d_in[1];
    const float* label_emb = (const float*)d_in[2];
    const float* label_adj = (const float*)d_in[3];
    const float* w_gcn3    = (const float*)d_in[4];
    const float* w_gcn5    = (const float*)d_in[5];
    const float* w_ll1     = (const float*)d_in[6];
    const float* b_ll1     = (const float*)d_in[7];
    const float* w_ll2     = (const float*)d_in[8];
    const float* b_ll2     = (const float*)d_in[9];
    const float* w_lin     = (const float*)d_in[10];
    const float* b_lin     = (const float*)d_in[11];
    const float* conv_w    = (const float*)d_in[12];
    const float* conv_b    = (const float*)d_in[13];
    const float* w_lin1    = (const float*)d_in[14];
    const float* b_lin1    = (const float*)d_in[15];

    float* out = (float*)d_out;   // [B*L] + [1]

    char* p = (char*)d_ws;
    auto alloc = [&](size_t bytes) { void* r = p; p += (bytes + 15) & ~(size_t)15; return r; };
    int*   cnt       = (int*)alloc(16);
    short* wkg       = (short*)alloc(WROWS * WP * 2);
    short* adj_bf    = (short*)alloc(200 * APAD * 2);
    short* E2_bf     = (short*)alloc(200 * 768 * 2);
    short* le_cat_bf = (short*)alloc(200 * 1536 * 2);
    short* qkh_bf    = (short*)alloc(200 * 2304 * 2);
    float* Amat      = (float*)alloc(200 * 200 * 4);
    short* Anorm_bf  = (short*)alloc(200 * APAD * 2);
    float* le_out_f  = (float*)alloc(200 * 768 * 4);
    short* le_out_bf = (short*)alloc(200 * 768 * 2);
    float* denom     = (float*)alloc(BB * DD * 4);
    short* doc_nb    = (short*)alloc((size_t)BB * SS * DD * 2);
    float* wla       = (float*)alloc((size_t)BB * SS * LL * 4);
    float* gatev     = (float*)alloc(BB * SS * 4);
    float* hpart     = (float*)alloc(BB * 8 * DD * 4);

    hipMemsetAsync(cnt, 0, 16, stream);

    chain_k<<<NBLK, 256, 0, stream>>>(
        label_emb, label_adj, w_gcn3, w_gcn5, w_ll1, b_ll1, w_ll2, b_ll2,
        w_lin, b_lin, conv_w, conv_b, doc_emb,
        wkg, adj_bf, E2_bf, le_cat_bf, qkh_bf, Amat, Anorm_bf,
        le_out_f, le_out_bf, denom, doc_nb, cnt);

    wla_k<<<256, 256, 0, stream>>>(doc_nb, le_out_bf, wla);

    (void)hipFuncSetAttribute((const void*)conv_max_k,
                              hipFuncAttributeMaxDynamicSharedMemorySize, 116736);
    conv_max_k<<<1024, 512, 116736, stream>>>(wla, wkg, gatev);

    tail_k<<<NBLK, 256, 0, stream>>>(doc_emb, gatev, denom, w_lin1, b_lin1,
                                     labels, hpart, out, cnt + 1);
}

// Round 11
// 298.320 us; speedup vs baseline: 1.8556x; 1.8446x over previous
//
#include <hip/hip_runtime.h>
#include <hip/hip_bf16.h>
#include <math.h>

// Problem constants
#define BB 8
#define SS 512
#define DD 768
#define LL 200

typedef __attribute__((ext_vector_type(8))) short bf16x8;
typedef __attribute__((ext_vector_type(4))) float f32x4;

__device__ inline short f2bf(float f) {
    unsigned u = __builtin_bit_cast(unsigned, f);
    unsigned r = (u + 0x7FFFu + ((u >> 16) & 1u)) >> 16;
    return (short)r;
}

// ---------------------------------------------------------------------------
// MFMA bf16 GEMM (R7-verified structure, BK=64, register prefetch)
//  C[M,N] = epi(A_bf16[M,lda] @ B + bias)
//  - A: bf16 row-major, K contiguous, zero-padded to Kp=ceil64(K)
//  - TB=true : B is bf16 [N][ldb] row-major (B^T layout)
//    TB=false: B is f32  [K][ldb] row-major (converted in staging)
//  - up to 3 B-regions along N (TB=false): cols>=nsplit -> Bv2, >=nsplit2 -> Bv3
//  - optional transposed bf16 side-output Ct for cols >= nsplitT:
//      Ct[(gn-nsplitT)*ldct + gm] = bf16(v)
// ---------------------------------------------------------------------------
#define LDP2 72   // LDS row pitch in bf16 (144 B = 9*16B odd)

template<int EPI, bool TB>
__global__ __launch_bounds__(256) void mgemm_k(
    const short* __restrict__ A, int lda,
    const void* __restrict__ Bv, int ldb,
    const float* __restrict__ bias,
    const void* __restrict__ Bv2, const float* __restrict__ bias2, int nsplit,
    const void* __restrict__ Bv3, const float* __restrict__ bias3, int nsplit2,
    float* __restrict__ Cf, int ldc,
    short* __restrict__ Cb, int ldcb,
    short* __restrict__ Ct, int ldct, int nsplitT,
    int M, int N, int K)
{
    __shared__ __align__(16) short As[64 * LDP2];
    __shared__ __align__(16) short Bs[64 * LDP2];
    const int tid = threadIdx.x;
    const int bm = blockIdx.y * 64;
    const int bn = blockIdx.x * 64;
    int bnb = bn;
    if (!TB) {
        if (bn >= nsplit2)      { Bv = Bv3; bias = bias3; bnb = bn - nsplit2; }
        else if (bn >= nsplit)  { Bv = Bv2; bias = bias2; bnb = bn - nsplit; }
    }
    const int w = tid >> 6, lane = tid & 63, g = lane >> 4, ln = lane & 15;
    const int Kp = (K + 63) & ~63;
    const int nt = Kp >> 6;

    const int ar = tid >> 2, ac = tid & 3;   // A / B(TB): row 0..63, 32B chunk 0..3
    const int bkk = tid >> 2, bc = tid & 3;  // B(f32): k-row 0..63, 16-float chunk

    f32x4 acc[4];
    #pragma unroll
    for (int i = 0; i < 4; ++i) acc[i] = (f32x4){0.f, 0.f, 0.f, 0.f};

    bf16x8 aR0 = {0,0,0,0,0,0,0,0}, aR1 = {0,0,0,0,0,0,0,0};
    bf16x8 bR0 = {0,0,0,0,0,0,0,0}, bR1 = {0,0,0,0,0,0,0,0};
    float  bF[16];
    #pragma unroll
    for (int j = 0; j < 16; ++j) bF[j] = 0.f;

    const int gmS = bm + ar;
    const bool aOk = (gmS < M);

    auto fetchA = [&](int k0) {
        if (aOk) {
            const short* p = A + (size_t)gmS * lda + k0 + ac * 16;
            aR0 = *(const bf16x8*)p;
            aR1 = *(const bf16x8*)(p + 8);
        }
    };
    auto fetchB = [&](int k0) {
        if (TB) {
            const short* Bt = (const short*)Bv;
            int gn = bn + ar;
            if (gn < N) {
                const short* p = Bt + (size_t)gn * ldb + k0 + ac * 16;
                bR0 = *(const bf16x8*)p;
                bR1 = *(const bf16x8*)(p + 8);
            }
        } else {
            const float* Bp = (const float*)Bv;
            int gk = k0 + bkk;
            int n0 = bnb + bc * 16;
            int gn0 = bn + bc * 16;
            if (gk < K) {
                const float* p = Bp + (size_t)gk * ldb + n0;
                if (gn0 + 16 <= N) {
                    #pragma unroll
                    for (int q = 0; q < 4; ++q) {
                        float4 x = *(const float4*)(p + q * 4);
                        bF[q*4+0]=x.x; bF[q*4+1]=x.y; bF[q*4+2]=x.z; bF[q*4+3]=x.w;
                    }
                } else {
                    #pragma unroll
                    for (int j = 0; j < 16; ++j) bF[j] = (gn0 + j < N) ? p[j] : 0.f;
                }
            } else {
                #pragma unroll
                for (int j = 0; j < 16; ++j) bF[j] = 0.f;
            }
        }
    };

    fetchA(0);
    fetchB(0);

    for (int t = 0; t < nt; ++t) {
        {
            short* pa = As + ar * LDP2 + ac * 16;
            *(bf16x8*)pa = aR0;
            *(bf16x8*)(pa + 8) = aR1;
        }
        if (TB) {
            short* pb = Bs + ar * LDP2 + ac * 16;
            *(bf16x8*)pb = bR0;
            *(bf16x8*)(pb + 8) = bR1;
        } else {
            #pragma unroll
            for (int j = 0; j < 16; ++j)
                Bs[(bc * 16 + j) * LDP2 + bkk] = f2bf(bF[j]);
        }
        __syncthreads();

        if (t + 1 < nt) {
            int k0 = (t + 1) << 6;
            fetchA(k0);
            fetchB(k0);
        }

        #pragma unroll
        for (int ks = 0; ks < 2; ++ks) {
            bf16x8 a = *(const bf16x8*)(As + (w * 16 + ln) * LDP2 + ks * 32 + g * 8);
            #pragma unroll
            for (int nb = 0; nb < 4; ++nb) {
                bf16x8 b = *(const bf16x8*)(Bs + (nb * 16 + ln) * LDP2 + ks * 32 + g * 8);
                acc[nb] = __builtin_amdgcn_mfma_f32_16x16x32_bf16(a, b, acc[nb], 0, 0, 0);
            }
        }
        __syncthreads();
    }

    #pragma unroll
    for (int nb = 0; nb < 4; ++nb) {
        int gn = bn + nb * 16 + ln;
        float bv = (bias && gn < N) ? bias[bnb + nb * 16 + ln] : 0.f;
        #pragma unroll
        for (int r = 0; r < 4; ++r) {
            int gm = bm + w * 16 + g * 4 + r;
            if (gm < M && gn < N) {
                float v = acc[nb][r] + bv;
                if (EPI == 1) v = (v >= 0.f) ? v : 0.2f * v;
                else if (EPI == 2) v = 1.f / (1.f + expf(-v));
                if (Cf) Cf[(size_t)gm * ldc + gn] = v;
                if (Cb) Cb[(size_t)gm * ldcb + gn] = f2bf(v);
                if (Ct && gn >= nsplitT)
                    Ct[(size_t)(gn - nsplitT) * ldct + gm] = f2bf(v);
            }
        }
    }
}

// ---------------------------------------------------------------------------
// prep: conv weights -> kappa-ordered bf16 [208][WP], kappa = kj*16+ki,
//       bias folded at (kj=0, ki=9); label_adj -> bf16 padded [200][256]
// ---------------------------------------------------------------------------
#define WP 168     // 336 B row pitch = 21 x 16B (odd) -> conflict-free b128
#define TP 24      // winT pitch: 48 B = 3 x 16B (odd)
#define WTR 217    // winT rows (guard to col 212)
#define WROWS 208
#define APAD 256   // K-pitch for K=200 operands (BK=64 tail-safe)
#define BIGN (1 << 30)

__global__ void prep_k(const float* __restrict__ cw, const float* __restrict__ cb,
                       const float* __restrict__ adj,
                       short* __restrict__ wkg, short* __restrict__ adj_bf)
{
    int idx = blockIdx.x * blockDim.x + threadIdx.x;
    if (idx < WROWS * WP) {
        int o = idx / WP, kk = idx % WP;
        int kj = kk >> 4, ki = kk & 15;
        float v = 0.f;
        if (o < LL && kj < 9) {
            if (ki < 9) v = cw[o * 81 + ki * 9 + kj];
            else if (ki == 9 && kj == 0) v = cb[o];
        }
        wkg[idx] = f2bf(v);
        return;
    }
    idx -= WROWS * WP;
    if (idx < LL * APAD) {
        int r = idx / APAD, c = idx % APAD;
        adj_bf[idx] = f2bf(c < LL ? adj[r * LL + c] : 0.f);
    }
}

// fused colsum + rsqrt + normalized adjacency: An[i][j] = bf16(A[j,i]d_i d_j)
__global__ void ca_k(const float* __restrict__ A, short* __restrict__ An)
{
    int i = blockIdx.x;
    int j = threadIdx.x;     // 256
    float si = 0.f, sj = 0.f;
    for (int l = 0; l < LL; ++l) {
        si += A[l * LL + i];
        if (j < LL) sj += A[l * LL + j];
    }
    float di = (si > 0.f) ? (1.f / sqrtf(si)) : 0.f;
    float dj = (sj > 0.f) ? (1.f / sqrtf(sj)) : 0.f;
    float v = (j < LL) ? A[j * LL + i] * di * dj : 0.f;
    An[i * APAD + j] = f2bf(v);
}

// l1-normalize columns of X [L,D] over L, emit bf16 (96 blocks x 8 cols x 32 lanes)
__global__ void l1n_k(const float* __restrict__ X, short* __restrict__ Xb)
{
    int c = threadIdx.x >> 5, r = threadIdx.x & 31;
    int col = blockIdx.x * 8 + c;              // 96*8 = 768
    float s = 0.f;
    for (int l = r; l < LL; l += 32) s += fabsf(X[l * DD + col]);
    #pragma unroll
    for (int off = 16; off > 0; off >>= 1) s += __shfl_xor(s, off, 64);
    float inv = 1.f / fmaxf(s, 1e-12f);
    for (int l = r; l < LL; l += 32)
        Xb[l * DD + col] = f2bf(X[l * DD + col] * inv);
}

// doc l1 denom: denom[b,d] = max(sum_s |doc[b,s,d]|, 1e-12)
__global__ void docsum_k(const float* __restrict__ doc, float* __restrict__ denom)
{
    int dc = blockIdx.x, b = blockIdx.y;
    int dx = threadIdx.x & 63, sy = threadIdx.x >> 6;
    int d = dc * 64 + dx;
    float s = 0.f;
    for (int t = sy; t < SS; t += 4)
        s += fabsf(doc[((size_t)b * SS + t) * DD + d]);
    __shared__ float red[4][64];
    red[sy][dx] = s;
    __syncthreads();
    if (sy == 0)
        denom[b * DD + d] = fmaxf(red[0][dx] + red[1][dx] + red[2][dx] + red[3][dx], 1e-12f);
}

// doc_nb = bf16(doc / denom), fully parallel float4
__global__ void docbf_k(const float* __restrict__ doc, const float* __restrict__ denom,
                        short* __restrict__ docb)
{
    int gid = blockIdx.x * blockDim.x + threadIdx.x;
    if (gid >= BB * SS * DD / 4) return;
    size_t base = (size_t)gid * 4;
    int d = (int)(base % DD);
    int b = (int)(base / ((size_t)SS * DD));
    float4 v = *(const float4*)(doc + base);
    float4 dn = *(const float4*)(denom + b * DD + d);
    short4 o;
    o.x = f2bf(v.x / dn.x);
    o.y = f2bf(v.y / dn.y);
    o.z = f2bf(v.z / dn.z);
    o.w = f2bf(v.w / dn.w);
    *(short4*)(docb + base) = o;
}

// ---------------------------------------------------------------------------
// conv kernel — UNCHANGED from R7 (verified, 62 us)
// ---------------------------------------------------------------------------
__global__ __launch_bounds__(512, 1) void conv_max_k(
    const float* __restrict__ wla,
    const short* __restrict__ wkg,
    float* __restrict__ gate)
{
    extern __shared__ short smem[];
    short* Wk   = smem;
    short* winT = Wk + WROWS * WP;
    short* wbf  = winT + 4 * WTR * TP;
    __shared__ float wredf[8];

    const int blk = blockIdx.x;
    const int b = blk >> 7;
    const int s0 = (blk & 127) << 2;
    const int tid = threadIdx.x;

    {
        const int4* src = (const int4*)wkg;
        int4* dst = (int4*)Wk;
        for (int i = tid; i < WROWS * WP / 8; i += 512) dst[i] = src[i];
    }
    for (int idx = tid; idx < 12 * 216; idx += 512) {
        int r = idx / 216, c = idx % 216;
        int sr = s0 - 4 + r, col = c - 4;
        float v = 0.f;
        if (sr >= 0 && sr < SS && col >= 0 && col < LL)
            v = wla[((size_t)b * SS + sr) * LL + col];
        wbf[idx] = f2bf(v);
    }
    __syncthreads();
    for (int idx = tid; idx < 4 * WTR; idx += 512) {
        int p = idx / WTR, r = idx % WTR;
        short vals[16];
        #pragma unroll
        for (int i = 0; i < 9; ++i) vals[i] = (r < 216) ? wbf[(p + i) * 216 + r] : (short)0;
        vals[9] = (short)0x3F80;
        #pragma unroll
        for (int i = 10; i < 16; ++i) vals[i] = 0;
        short* dstp = winT + (p * WTR + r) * TP;
        *(bf16x8*)dstp = *(const bf16x8*)vals;
        *(bf16x8*)(dstp + 8) = *(const bf16x8*)(vals + 8);
    }
    __syncthreads();

    const int w = tid >> 6;
    const int p = w >> 1;
    const int h = w & 1;
    const int lane = tid & 63;
    const int g = lane >> 4;
    const int ln = lane & 15;
    const short* WT = winT + p * WTR * TP;

    bf16x8 Af[7][5];
    #pragma unroll
    for (int s = 0; s < 7; ++s) {
        int st = h * 7 + s;
        if (st > 12) st = 12;
        #pragma unroll
        for (int j = 0; j < 5; ++j)
            Af[s][j] = *(const bf16x8*)(Wk + (st * 16 + ln) * WP + j * 32 + g * 8);
    }

    float lm = -INFINITY;

    auto loadB = [&](int nt, bf16x8 (&Bf)[5]) {
        #pragma unroll
        for (int j = 0; j < 5; ++j)
            Bf[j] = *(const bf16x8*)(WT + (nt * 16 + ln + 2 * j + (g >> 1)) * TP + (g & 1) * 8);
    };
    auto compute = [&](int nt, const bf16x8 (&Bf)[5]) {
        #pragma unroll
        for (int s = 0; s < 7; ++s) {
            if (h == 0 || s < 6) {
                int st = h * 7 + s;
                f32x4 acc = {0.f, 0.f, 0.f, 0.f};
                #pragma unroll
                for (int j = 0; j < 5; ++j)
                    acc = __builtin_amdgcn_mfma_f32_16x16x32_bf16(Af[s][j], Bf[j], acc, 0, 0, 0);
                float t = fmaxf(fmaxf(acc[0], acc[1]), fmaxf(acc[2], acc[3]));
                bool ok = (st < 12 || g < 2) && (nt < 12 || ln < 8);
                lm = ok ? fmaxf(lm, t) : lm;
            }
        }
    };

    bf16x8 B0[5], B1[5];
    loadB(0, B0);
    for (int nt = 0; nt < 12; nt += 2) {
        loadB(nt + 1, B1);
        compute(nt, B0);
        loadB(nt + 2, B0);
        compute(nt + 1, B1);
    }
    compute(12, B0);

    #pragma unroll
    for (int off = 32; off > 0; off >>= 1)
        lm = fmaxf(lm, __shfl_xor(lm, off, 64));
    if (lane == 0) wredf[w] = lm;
    __syncthreads();
    if (tid < 4)
        gate[((size_t)b << 9) + s0 + tid] = tanhf(fmaxf(wredf[2 * tid], wredf[2 * tid + 1]));
}

// ---------------------------------------------------------------------------
// h_enc two-phase (R7-verified)
// ---------------------------------------------------------------------------
__global__ void henc_part_k(const float* __restrict__ doc, const float* __restrict__ gate,
                            float* __restrict__ hpart)
{
    int dc = blockIdx.x, sc = blockIdx.y, b = blockIdx.z;
    int dx = threadIdx.x & 63, sy = threadIdx.x >> 6;
    int d = dc * 64 + dx;
    float s = 0.f;
    for (int t = sy; t < 64; t += 4) {
        int srow = sc * 64 + t;
        s = fmaf(doc[((size_t)b * SS + srow) * DD + d], gate[b * SS + srow], s);
    }
    __shared__ float red[4][64];
    red[sy][dx] = s;
    __syncthreads();
    if (sy == 0)
        hpart[((size_t)b * 8 + sc) * DD + d] = red[0][dx] + red[1][dx] + red[2][dx] + red[3][dx];
}

__global__ void final2_k(const float* __restrict__ hpart, const float* __restrict__ denom,
                         const float* __restrict__ W, const float* __restrict__ bias,
                         float* __restrict__ out)
{
    int b = blockIdx.x, tid = threadIdx.x;
    __shared__ float hb[DD];
    for (int idx = tid; idx < DD; idx += 256) {
        float s = 0.f;
        #pragma unroll
        for (int sc = 0; sc < 8; ++sc) s += hpart[((size_t)b * 8 + sc) * DD + idx];
        hb[idx] = s / denom[b * DD + idx];
    }
    __syncthreads();
    int l = tid;
    if (l < LL) {
        float acc = bias[l];
        for (int d = 0; d < DD; ++d) acc = fmaf(hb[d], W[d * LL + l], acc);
        out[b * LL + l] = 1.f / (1.f + expf(-acc));
    }
}

__global__ void loss_k(const float* __restrict__ out, const float* __restrict__ labels,
                       float* __restrict__ loss_out)
{
    float s = 0.f;
    for (int i = threadIdx.x; i < BB * LL; i += 256) {
        float p = out[i];
        p = fminf(fmaxf(p, 1e-7f), 1.f - 1e-7f);
        float y = labels[i];
        s += y * logf(p) + (1.f - y) * logf(1.f - p);
    }
    #pragma unroll
    for (int off = 32; off > 0; off >>= 1) s += __shfl_down(s, off, 64);
    __shared__ float ws[4];
    if ((threadIdx.x & 63) == 0) ws[threadIdx.x >> 6] = s;
    __syncthreads();
    if (threadIdx.x == 0)
        loss_out[0] = -(ws[0] + ws[1] + ws[2] + ws[3]) / (float)(BB * LL);
}

// ---------------------------------------------------------------------------
static void mgemm(hipStream_t st, int epi, bool tb,
                  const short* A, int lda, const void* B, int ldb,
                  const float* bias,
                  const void* B2, const float* bias2, int nsplit,
                  const void* B3, const float* bias3, int nsplit2,
                  float* Cf, int ldc, short* Cb, int ldcb,
                  short* Ct, int ldct, int nsplitT,
                  int M, int N, int K)
{
    dim3 g((N + 63) / 64, (M + 63) / 64);
    if (!tb) {
        if (epi == 0)      mgemm_k<0, false><<<g, 256, 0, st>>>(A, lda, B, ldb, bias, B2, bias2, nsplit, B3, bias3, nsplit2, Cf, ldc, Cb, ldcb, Ct, ldct, nsplitT, M, N, K);
        else if (epi == 1) mgemm_k<1, false><<<g, 256, 0, st>>>(A, lda, B, ldb, bias, B2, bias2, nsplit, B3, bias3, nsplit2, Cf, ldc, Cb, ldcb, Ct, ldct, nsplitT, M, N, K);
        else               mgemm_k<2, false><<<g, 256, 0, st>>>(A, lda, B, ldb, bias, B2, bias2, nsplit, B3, bias3, nsplit2, Cf, ldc, Cb, ldcb, Ct, ldct, nsplitT, M, N, K);
    } else {
        if (epi == 0)      mgemm_k<0, true><<<g, 256, 0, st>>>(A, lda, B, ldb, bias, B2, bias2, nsplit, B3, bias3, nsplit2, Cf, ldc, Cb, ldcb, Ct, ldct, nsplitT, M, N, K);
        else if (epi == 1) mgemm_k<1, true><<<g, 256, 0, st>>>(A, lda, B, ldb, bias, B2, bias2, nsplit, B3, bias3, nsplit2, Cf, ldc, Cb, ldcb, Ct, ldct, nsplitT, M, N, K);
        else               mgemm_k<2, true><<<g, 256, 0, st>>>(A, lda, B, ldb, bias, B2, bias2, nsplit, B3, bias3, nsplit2, Cf, ldc, Cb, ldcb, Ct, ldct, nsplitT, M, N, K);
    }
}

extern "C" void kernel_launch(void* const* d_in, const int* in_sizes, int n_in,
                              void* d_out, int out_size, void* d_ws, size_t ws_size,
                              hipStream_t stream)
{
    const float* doc_emb   = (const float*)d_in[0];
    const float* labels    = (const float*)d_in[1];
    const float* label_emb = (const float*)d_in[2];
    const float* label_adj = (const float*)d_in[3];
    const float* w_gcn3    = (const float*)d_in[4];
    const float* w_gcn5    = (const float*)d_in[5];
    const float* w_ll1     = (const float*)d_in[6];
    const float* b_ll1     = (const float*)d_in[7];
    const float* w_ll2     = (const float*)d_in[8];
    const float* b_ll2     = (const float*)d_in[9];
    const float* w_lin     = (const float*)d_in[10];
    const float* b_lin     = (const float*)d_in[11];
    const float* conv_w    = (const float*)d_in[12];
    const float* conv_b    = (const float*)d_in[13];
    const float* w_lin1    = (const float*)d_in[14];
    const float* b_lin1    = (const float*)d_in[15];

    float* out = (float*)d_out;   // [B*L] + [1]

    char* p = (char*)d_ws;
    auto alloc = [&](size_t bytes) { void* r = p; p += (bytes + 15) & ~(size_t)15; return r; };
    short* wkg       = (short*)alloc(WROWS * WP * 2);
    short* adj_bf    = (short*)alloc(200 * APAD * 2);
    short* E2_bf     = (short*)alloc(200 * 768 * 2);
    short* le_cat_bf = (short*)alloc(200 * 1536 * 2);   // [le | d_le]
    short* qkh_bf    = (short*)alloc(200 * 2304 * 2);   // [q | k | H]
    short* Ht        = (short*)alloc(768 * 256 * 2);    // H^T, K-pitch 256
    float* Amat      = (float*)alloc(200 * 200 * 4);
    short* Anorm_bf  = (short*)alloc(200 * APAD * 2);
    float* le_out_f  = (float*)alloc(200 * 768 * 4);
    short* le_out_bf = (short*)alloc(200 * 768 * 2);
    float* denom     = (float*)alloc(BB * DD * 4);
    short* doc_nb    = (short*)alloc((size_t)BB * SS * DD * 2);
    float* wla       = (float*)alloc((size_t)BB * SS * LL * 4);
    float* gatev     = (float*)alloc(BB * SS * 4);
    float* hpart     = (float*)alloc(BB * 8 * DD * 4);

    // prep (conv weights kappa-order + bias fold, adj pad)
    prep_k<<<(WROWS * WP + LL * APAD + 255) / 256, 256, 0, stream>>>(
        conv_w, conv_b, label_adj, wkg, adj_bf);
    // E2 = adj @ emb   [200,768] K=200
    mgemm(stream, 0, false, adj_bf, APAD, label_emb, DD, nullptr,
          nullptr, nullptr, BIGN, nullptr, nullptr, BIGN,
          nullptr, 0, E2_bf, DD, nullptr, 0, BIGN, LL, DD, LL);
    // le = leaky(E2 @ W3) -> f32-free: bf16 into le_cat[:, :768]
    mgemm(stream, 1, false, E2_bf, DD, w_gcn3, DD, nullptr,
          nullptr, nullptr, BIGN, nullptr, nullptr, BIGN,
          nullptr, 0, le_cat_bf, 1536, nullptr, 0, BIGN, LL, DD, DD);
    // [q|k|H] = le @ [w_ll1|w_ll2|w_gcn5] + [b1|b2|0]  N=2304; H also -> Ht^T
    mgemm(stream, 0, false, le_cat_bf, 1536, w_ll1, DD, b_ll1,
          w_ll2, b_ll2, DD, w_gcn5, nullptr, 2 * DD,
          nullptr, 0, qkh_bf, 2304, Ht, 256, 2 * DD, LL, 3 * DD, DD);
    // A = sigmoid(q @ k^T)  [200,200] K=768
    mgemm(stream, 2, true, qkh_bf, 2304, qkh_bf + DD, 2304, nullptr,
          nullptr, nullptr, BIGN, nullptr, nullptr, BIGN,
          Amat, LL, nullptr, 0, nullptr, 0, BIGN, LL, LL, DD);
    // fused colsum + rsqrt + normalized adjacency
    ca_k<<<LL, 256, 0, stream>>>(Amat, Anorm_bf);
    // d_le = leaky(Anorm @ H)  K=200 via Ht (B^T layout) -> le_cat[:, 768:]
    mgemm(stream, 1, true, Anorm_bf, APAD, Ht, 256, nullptr,
          nullptr, nullptr, BIGN, nullptr, nullptr, BIGN,
          nullptr, 0, le_cat_bf + DD, 1536, nullptr, 0, BIGN, LL, DD, LL);
    // le_out = le_cat @ w_lin + b_lin   K=1536
    mgemm(stream, 0, false, le_cat_bf, 1536, w_lin, DD, b_lin,
          nullptr, nullptr, BIGN, nullptr, nullptr, BIGN,
          le_out_f, DD, nullptr, 0, nullptr, 0, BIGN, LL, DD, 2 * DD);
    // l1 normalize over L -> bf16 (96 blocks)
    l1n_k<<<96, 256, 0, stream>>>(le_out_f, le_out_bf);
    // doc l1 norm (two-phase) -> denom + bf16 doc
    docsum_k<<<dim3(12, 8), 256, 0, stream>>>(doc_emb, denom);
    docbf_k<<<(BB * SS * DD / 4 + 255) / 256, 256, 0, stream>>>(doc_emb, denom, doc_nb);
    // wla = doc_n @ le_out^T   [4096,200] K=768
    mgemm(stream, 0, true, doc_nb, DD, le_out_bf, DD, nullptr,
          nullptr, nullptr, BIGN, nullptr, nullptr, BIGN,
          wla, LL, nullptr, 0, nullptr, 0, BIGN, BB * SS, LL, DD);
    // conv + max + tanh
    (void)hipFuncSetAttribute((const void*)conv_max_k,
                              hipFuncAttributeMaxDynamicSharedMemorySize, 116736);
    conv_max_k<<<1024, 512, 116736, stream>>>(wla, wkg, gatev);
    // h_enc partials + final + loss
    henc_part_k<<<dim3(12, 8, 8), 256, 0, stream>>>(doc_emb, gatev, hpart);
    final2_k<<<BB, 256, 0, stream>>>(hpart, denom, w_lin1, b_lin1, out);
    loss_k<<<1, 256, 0, stream>>>(out, labels, out + BB * LL);
}